// Round 2
// baseline (240.976 us; speedup 1.0000x reference)
//
#include <hip/hip_runtime.h>
#include <hip/hip_bf16.h>
#include <cstdint>
#include <cstddef>

typedef _Float16 f16;
typedef _Float16 f16x8 __attribute__((ext_vector_type(8)));
typedef _Float16 f16x4 __attribute__((ext_vector_type(4)));
typedef float    f32x4 __attribute__((ext_vector_type(4)));

#define B_SZ   8
#define NPOS   3136      // 56*56
#define CIN    256
#define CI     128       // C_INTER
#define CO     256
#define MTOT   (B_SZ*NPOS)   // 25088

// ---------------------------------------------------------------------------
// Kernel 0: weight prep — transpose + fp32->fp16
//   wprojT[384][256] : rows 0-127 = w_theta^T, 128-255 = w_phi^T, 256-383 = w_g^T
//   woutT [256][128] : w_out^T
// ---------------------------------------------------------------------------
__global__ void prep_weights(const float* __restrict__ wt, const float* __restrict__ wp,
                             const float* __restrict__ wg, const float* __restrict__ wo,
                             f16* __restrict__ wprojT, f16* __restrict__ woutT) {
    int o = blockIdx.x;
    int k = threadIdx.x;
    if (o < 384) {
        const float* w = (o < 128) ? wt : (o < 256) ? wp : wg;
        int d = o & 127;
        wprojT[o * 256 + k] = (f16)w[k * 128 + d];
    } else {
        int oo = o - 384;           // 0..255
        if (k < 128) woutT[oo * 128 + k] = (f16)wo[k * 256 + oo];
    }
}

// ---------------------------------------------------------------------------
// Kernel 1: fused projection GEMM.  C[25088, 384] = x[25088,256] @ Wcat[256,384]
//   theta/phi stored [B][N][128] row-major f16; g stored transposed [B][128][N]
// ---------------------------------------------------------------------------
__launch_bounds__(256)
__global__ void proj_gemm(const float* __restrict__ x, const f16* __restrict__ wprojT,
                          const float* __restrict__ bth, const float* __restrict__ bph,
                          const float* __restrict__ bgg,
                          f16* __restrict__ theta, f16* __restrict__ phi,
                          f16* __restrict__ gt) {
    const int mt  = blockIdx.x;          // 0..391
    const int ct  = blockIdx.y;          // 0..5
    const int m0  = mt * 64;
    const int tid = threadIdx.x;
    const int w   = tid >> 6;
    const int l   = tid & 63;
    const int lrow = l & 15;
    const int lk8  = (l >> 4) * 8;

    __shared__ alignas(16) f16 At[64 * 256];   // 32 KB, XOR-swizzled rows

    // stage A tile: 64 rows x 256 cols fp32 -> fp16 (swizzle: elem-idx ^= (row&7)<<3)
    #pragma unroll
    for (int i = 0; i < 16; ++i) {
        int c   = tid + 256 * i;           // 4096 chunks of 4 floats
        int row = c >> 6;
        int col = (c & 63) * 4;
        f32x4 v = *reinterpret_cast<const f32x4*>(&x[(size_t)(m0 + row) * CIN + col]);
        f16x4 t;
        t[0] = (f16)v[0]; t[1] = (f16)v[1]; t[2] = (f16)v[2]; t[3] = (f16)v[3];
        *reinterpret_cast<f16x4*>(&At[row * 256 + (col ^ ((row & 7) << 3))]) = t;
    }
    __syncthreads();

    f32x4 acc[4];
    #pragma unroll
    for (int c0 = 0; c0 < 4; ++c0) acc[c0] = (f32x4){0.f, 0.f, 0.f, 0.f};

    const int c0base = ct * 64;
    const int arow   = w * 16 + lrow;

    #pragma unroll
    for (int kt = 0; kt < 8; ++kt) {
        int kk = kt * 32 + lk8;
        f16x8 a = *reinterpret_cast<const f16x8*>(&At[arow * 256 + (kk ^ ((arow & 7) << 3))]);
        #pragma unroll
        for (int c0 = 0; c0 < 4; ++c0) {
            int col = c0base + c0 * 16 + lrow;
            f16x8 b = *reinterpret_cast<const f16x8*>(&wprojT[col * 256 + kk]);
            acc[c0] = __builtin_amdgcn_mfma_f32_16x16x32_f16(a, b, acc[c0], 0, 0, 0);
        }
    }

    // epilogue: bias + scatter to theta / phi / g^T
    #pragma unroll
    for (int c0 = 0; c0 < 4; ++c0) {
        int col = c0base + c0 * 16 + lrow;     // 0..383
        int sel = col >> 7;
        int d   = col & 127;
        float bias = (sel == 0) ? bth[d] : (sel == 1) ? bph[d] : bgg[d];
        #pragma unroll
        for (int j = 0; j < 4; ++j) {
            int m = m0 + w * 16 + (l >> 4) * 4 + j;
            int b = m / NPOS;
            int n = m - b * NPOS;
            f16 hv = (f16)(acc[c0][j] + bias);
            if (sel == 0)      theta[((size_t)b * NPOS + n) * CI + d] = hv;
            else if (sel == 1) phi  [((size_t)b * NPOS + n) * CI + d] = hv;
            else               gt   [((size_t)b * CI + d) * NPOS + n] = hv;
        }
    }
}

// ---------------------------------------------------------------------------
// Kernel 2: flash attention.  y[b][n][d] = softmax(theta phi^T) g
//   block: 256 thr (4 waves), 64 Q rows/block (16 per wave), KV tiles of 64
// ---------------------------------------------------------------------------
__launch_bounds__(256)
__global__ void attn(const f16* __restrict__ theta, const f16* __restrict__ phi,
                     const f16* __restrict__ gt, f16* __restrict__ y) {
    const int qt  = blockIdx.x;   // 0..48
    const int b   = blockIdx.y;   // 0..7
    const int tid = threadIdx.x;
    const int w   = tid >> 6;
    const int l   = tid & 63;
    const int lrow = l & 15;
    const int lk8  = (l >> 4) * 8;

    __shared__ alignas(16) f16 Kt[64 * 128];    // phi tile, rows=kv, 16 KB
    __shared__ alignas(16) f16 Vt[128 * 64];    // g^T tile, rows=d, 16 KB
    __shared__ alignas(16) f16 Pl[4][16 * 64];  // per-wave P tile, 8 KB

    const f16* thB = theta + (size_t)b * NPOS * CI;
    const f16* phB = phi   + (size_t)b * NPOS * CI;
    const f16* gtB = gt    + (size_t)b * CI * NPOS;

    const int q0 = qt * 64 + w * 16;

    // Q fragments (held for whole kernel)
    f16x8 aq[4];
    #pragma unroll
    for (int kt = 0; kt < 4; ++kt)
        aq[kt] = *reinterpret_cast<const f16x8*>(&thB[(size_t)(q0 + lrow) * CI + kt * 32 + lk8]);

    f32x4 o[8];
    #pragma unroll
    for (int d0 = 0; d0 < 8; ++d0) o[d0] = (f32x4){0.f, 0.f, 0.f, 0.f};
    float mrow[4], lsum[4];
    #pragma unroll
    for (int j = 0; j < 4; ++j) { mrow[j] = -1e30f; lsum[j] = 0.f; }

    for (int t = 0; t < NPOS / 64; ++t) {
        const int kv0 = t * 64;
        __syncthreads();                    // previous iteration's LDS reads done

        // stage K tile: 64 rows(kv) x 128(d), swizzled
        #pragma unroll
        for (int i = 0; i < 4; ++i) {
            int c = tid + 256 * i;          // 1024 chunks of 8 f16
            int row  = c >> 4;
            int dcol = (c & 15) * 8;
            f16x8 v = *reinterpret_cast<const f16x8*>(&phB[(size_t)(kv0 + row) * CI + dcol]);
            *reinterpret_cast<f16x8*>(&Kt[row * 128 + (dcol ^ ((row & 7) << 3))]) = v;
        }
        // stage V tile: 128 rows(d) x 64(kv), swizzled
        #pragma unroll
        for (int i = 0; i < 4; ++i) {
            int c = tid + 256 * i;
            int row  = c >> 3;              // d
            int kcol = (c & 7) * 8;
            f16x8 v = *reinterpret_cast<const f16x8*>(&gtB[(size_t)row * NPOS + kv0 + kcol]);
            *reinterpret_cast<f16x8*>(&Vt[row * 64 + (kcol ^ ((row & 7) << 3))]) = v;
        }
        __syncthreads();

        // S = Q K^T   (16 q-rows x 64 kv-cols per wave)
        f32x4 s[4];
        #pragma unroll
        for (int c0 = 0; c0 < 4; ++c0) s[c0] = (f32x4){0.f, 0.f, 0.f, 0.f};
        #pragma unroll
        for (int kt = 0; kt < 4; ++kt) {
            #pragma unroll
            for (int c0 = 0; c0 < 4; ++c0) {
                int krow = c0 * 16 + lrow;
                f16x8 bk = *reinterpret_cast<const f16x8*>(
                    &Kt[krow * 128 + ((kt * 32 + lk8) ^ ((krow & 7) << 3))]);
                s[c0] = __builtin_amdgcn_mfma_f32_16x16x32_f16(aq[kt], bk, s[c0], 0, 0, 0);
            }
        }

        // online softmax (row j lives in lanes (l>>4)-group, cols in l&15)
        #pragma unroll
        for (int j = 0; j < 4; ++j) {
            float rm = fmaxf(fmaxf(s[0][j], s[1][j]), fmaxf(s[2][j], s[3][j]));
            rm = fmaxf(rm, __shfl_xor(rm, 1));
            rm = fmaxf(rm, __shfl_xor(rm, 2));
            rm = fmaxf(rm, __shfl_xor(rm, 4));
            rm = fmaxf(rm, __shfl_xor(rm, 8));
            float mnew  = fmaxf(mrow[j], rm);
            float scale = __expf(mrow[j] - mnew);
            mrow[j] = mnew;
            float ps = 0.f;
            #pragma unroll
            for (int c0 = 0; c0 < 4; ++c0) {
                float p = __expf(s[c0][j] - mnew);
                s[c0][j] = p;
                ps += p;
            }
            ps += __shfl_xor(ps, 1);
            ps += __shfl_xor(ps, 2);
            ps += __shfl_xor(ps, 4);
            ps += __shfl_xor(ps, 8);
            lsum[j] = lsum[j] * scale + ps;
            #pragma unroll
            for (int d0 = 0; d0 < 8; ++d0) o[d0][j] *= scale;
            // spill P row to per-wave LDS (swizzled) for A-fragment re-read
            int prow = (l >> 4) * 4 + j;
            #pragma unroll
            for (int c0 = 0; c0 < 4; ++c0) {
                int kv = c0 * 16 + lrow;
                Pl[w][prow * 64 + (kv ^ ((prow & 7) << 3))] = (f16)s[c0][j];
            }
        }
        asm volatile("s_waitcnt lgkmcnt(0)" ::: "memory");   // per-wave P write->read

        // O += P V
        #pragma unroll
        for (int kt2 = 0; kt2 < 2; ++kt2) {
            f16x8 pa = *reinterpret_cast<const f16x8*>(
                &Pl[w][lrow * 64 + ((kt2 * 32 + lk8) ^ ((lrow & 7) << 3))]);
            #pragma unroll
            for (int d0 = 0; d0 < 8; ++d0) {
                int vrow = d0 * 16 + lrow;
                f16x8 bv = *reinterpret_cast<const f16x8*>(
                    &Vt[vrow * 64 + ((kt2 * 32 + lk8) ^ ((vrow & 7) << 3))]);
                o[d0] = __builtin_amdgcn_mfma_f32_16x16x32_f16(pa, bv, o[d0], 0, 0, 0);
            }
        }
    }

    // epilogue: normalize and store y (f16)
    #pragma unroll
    for (int j = 0; j < 4; ++j) {
        float inv  = 1.f / lsum[j];
        int   qrow = q0 + (l >> 4) * 4 + j;
        #pragma unroll
        for (int d0 = 0; d0 < 8; ++d0) {
            int d = d0 * 16 + lrow;
            y[((size_t)b * NPOS + qrow) * CI + d] = (f16)(o[d0][j] * inv);
        }
    }
}

// ---------------------------------------------------------------------------
// Kernel 3: out = x + y @ w_out + b_out
// ---------------------------------------------------------------------------
__launch_bounds__(256)
__global__ void out_proj(const f16* __restrict__ y, const f16* __restrict__ woutT,
                         const float* __restrict__ bout, const float* __restrict__ x,
                         float* __restrict__ out) {
    const int mt  = blockIdx.x;   // 0..391
    const int ct  = blockIdx.y;   // 0..3
    const int tid = threadIdx.x;
    const int w   = tid >> 6;
    const int l   = tid & 63;
    const int lrow = l & 15;
    const int lk8  = (l >> 4) * 8;
    const int m0   = mt * 64 + w * 16;

    f32x4 acc[4];
    #pragma unroll
    for (int c0 = 0; c0 < 4; ++c0) acc[c0] = (f32x4){0.f, 0.f, 0.f, 0.f};

    #pragma unroll
    for (int kt = 0; kt < 4; ++kt) {
        f16x8 a = *reinterpret_cast<const f16x8*>(&y[(size_t)(m0 + lrow) * CI + kt * 32 + lk8]);
        #pragma unroll
        for (int c0 = 0; c0 < 4; ++c0) {
            int oc = ct * 64 + c0 * 16 + lrow;
            f16x8 bb = *reinterpret_cast<const f16x8*>(&woutT[oc * CI + kt * 32 + lk8]);
            acc[c0] = __builtin_amdgcn_mfma_f32_16x16x32_f16(a, bb, acc[c0], 0, 0, 0);
        }
    }

    #pragma unroll
    for (int c0 = 0; c0 < 4; ++c0) {
        int oc = ct * 64 + c0 * 16 + lrow;
        float bias = bout[oc];
        #pragma unroll
        for (int j = 0; j < 4; ++j) {
            size_t m = (size_t)m0 + (l >> 4) * 4 + j;
            out[m * CO + oc] = acc[c0][j] + bias + x[m * CO + oc];
        }
    }
}

// ---------------------------------------------------------------------------
extern "C" void kernel_launch(void* const* d_in, const int* in_sizes, int n_in,
                              void* d_out, int out_size, void* d_ws, size_t ws_size,
                              hipStream_t stream) {
    const float* x  = (const float*)d_in[0];
    const float* wt = (const float*)d_in[1];
    const float* bt = (const float*)d_in[2];
    const float* wp = (const float*)d_in[3];
    const float* bp = (const float*)d_in[4];
    const float* wg = (const float*)d_in[5];
    const float* bg = (const float*)d_in[6];
    const float* wo = (const float*)d_in[7];
    const float* bo = (const float*)d_in[8];
    float* out = (float*)d_out;

    char* ws = (char*)d_ws;
    const size_t SZ_PROJT = 384 * 256 * sizeof(f16);   // 196608
    const size_t SZ_OUTT  = 256 * 128 * sizeof(f16);   // 65536
    const size_t SZ_MAT   = (size_t)B_SZ * NPOS * CI * sizeof(f16);  // 6422528
    f16* wprojT = (f16*)ws;
    f16* woutT  = (f16*)(ws + SZ_PROJT);
    f16* theta  = (f16*)(ws + SZ_PROJT + SZ_OUTT);
    f16* phi    = (f16*)(ws + SZ_PROJT + SZ_OUTT + SZ_MAT);
    f16* gt     = (f16*)(ws + SZ_PROJT + SZ_OUTT + 2 * SZ_MAT);
    f16* yb     = (f16*)(ws + SZ_PROJT + SZ_OUTT + 3 * SZ_MAT);

    hipLaunchKernelGGL(prep_weights, dim3(640), dim3(256), 0, stream,
                       wt, wp, wg, wo, wprojT, woutT);
    hipLaunchKernelGGL(proj_gemm, dim3(392, 6), dim3(256), 0, stream,
                       x, wprojT, bt, bp, bg, theta, phi, gt);
    hipLaunchKernelGGL(attn, dim3(NPOS / 64, B_SZ), dim3(256), 0, stream,
                       theta, phi, gt, yb);
    hipLaunchKernelGGL(out_proj, dim3(392, 4), dim3(256), 0, stream,
                       yb, woutT, bo, x, out);
}

// Round 3
// 218.693 us; speedup vs baseline: 1.1019x; 1.1019x over previous
//
#include <hip/hip_runtime.h>
#include <hip/hip_bf16.h>
#include <cstdint>
#include <cstddef>

typedef _Float16 f16;
typedef _Float16 f16x8 __attribute__((ext_vector_type(8)));
typedef _Float16 f16x4 __attribute__((ext_vector_type(4)));
typedef float    f32x4 __attribute__((ext_vector_type(4)));

#define B_SZ   8
#define NPOS   3136      // 56*56
#define CIN    256
#define CI     128       // C_INTER
#define CO     256
#define MTOT   (B_SZ*NPOS)   // 25088
#define NT     49            // KV tiles of 64

// ---------------------------------------------------------------------------
// Kernel 0: weight prep — transpose + fp32->fp16
// ---------------------------------------------------------------------------
__global__ void prep_weights(const float* __restrict__ wt, const float* __restrict__ wp,
                             const float* __restrict__ wg, const float* __restrict__ wo,
                             f16* __restrict__ wprojT, f16* __restrict__ woutT) {
    int o = blockIdx.x;
    int k = threadIdx.x;
    if (o < 384) {
        const float* w = (o < 128) ? wt : (o < 256) ? wp : wg;
        int d = o & 127;
        wprojT[o * 256 + k] = (f16)w[k * 128 + d];
    } else {
        int oo = o - 384;           // 0..255
        if (k < 128) woutT[oo * 128 + k] = (f16)wo[k * 256 + oo];
    }
}

// ---------------------------------------------------------------------------
// Kernel 1: fused projection GEMM.  C[25088, 384] = x[25088,256] @ Wcat[256,384]
//   One block per 64-row tile; all 6 column tiles in an inner loop (x staged once).
// ---------------------------------------------------------------------------
__launch_bounds__(256)
__global__ void proj_gemm(const float* __restrict__ x, const f16* __restrict__ wprojT,
                          const float* __restrict__ bth, const float* __restrict__ bph,
                          const float* __restrict__ bgg,
                          f16* __restrict__ theta, f16* __restrict__ phi,
                          f16* __restrict__ gt) {
    const int mt  = blockIdx.x;          // 0..391
    const int m0  = mt * 64;
    const int tid = threadIdx.x;
    const int w   = tid >> 6;
    const int l   = tid & 63;
    const int lrow = l & 15;
    const int lk8  = (l >> 4) * 8;

    __shared__ alignas(16) f16 At[64 * 256];   // 32 KB, XOR-swizzled rows

    #pragma unroll
    for (int i = 0; i < 16; ++i) {
        int c   = tid + 256 * i;           // 4096 chunks of 4 floats
        int row = c >> 6;
        int col = (c & 63) * 4;
        f32x4 v = *reinterpret_cast<const f32x4*>(&x[(size_t)(m0 + row) * CIN + col]);
        f16x4 t;
        t[0] = (f16)v[0]; t[1] = (f16)v[1]; t[2] = (f16)v[2]; t[3] = (f16)v[3];
        *reinterpret_cast<f16x4*>(&At[row * 256 + (col ^ ((row & 7) << 3))]) = t;
    }
    __syncthreads();

    const int arow = w * 16 + lrow;
    f16x8 af[8];
    #pragma unroll
    for (int kt = 0; kt < 8; ++kt) {
        int kk = kt * 32 + lk8;
        af[kt] = *reinterpret_cast<const f16x8*>(&At[arow * 256 + (kk ^ ((arow & 7) << 3))]);
    }

    for (int ct = 0; ct < 6; ++ct) {
        f32x4 acc[4];
        #pragma unroll
        for (int c0 = 0; c0 < 4; ++c0) acc[c0] = (f32x4){0.f, 0.f, 0.f, 0.f};
        const int c0base = ct * 64;
        #pragma unroll
        for (int kt = 0; kt < 8; ++kt) {
            int kk = kt * 32 + lk8;
            #pragma unroll
            for (int c0 = 0; c0 < 4; ++c0) {
                int col = c0base + c0 * 16 + lrow;
                f16x8 b = *reinterpret_cast<const f16x8*>(&wprojT[col * 256 + kk]);
                acc[c0] = __builtin_amdgcn_mfma_f32_16x16x32_f16(af[kt], b, acc[c0], 0, 0, 0);
            }
        }
        #pragma unroll
        for (int c0 = 0; c0 < 4; ++c0) {
            int col = c0base + c0 * 16 + lrow;     // 0..383
            int sel = col >> 7;
            int d   = col & 127;
            float bias = (sel == 0) ? bth[d] : (sel == 1) ? bph[d] : bgg[d];
            #pragma unroll
            for (int j = 0; j < 4; ++j) {
                int m = m0 + w * 16 + (l >> 4) * 4 + j;
                int b = m / NPOS;
                int n = m - b * NPOS;
                f16 hv = (f16)(acc[c0][j] + bias);
                if (sel == 0)      theta[((size_t)b * NPOS + n) * CI + d] = hv;
                else if (sel == 1) phi  [((size_t)b * NPOS + n) * CI + d] = hv;
                else               gt   [((size_t)b * CI + d) * NPOS + n] = hv;
            }
        }
    }
}

// ---------------------------------------------------------------------------
// Kernel 2: flash attention, KV-split. Block (qt, b, s) handles KV tiles
//   [t0,t1) with independent online softmax; writes normalized partial O (f16)
//   and per-row (m, l) for the merge.
// ---------------------------------------------------------------------------
__launch_bounds__(256)
__global__ void attn_partial(const f16* __restrict__ theta, const f16* __restrict__ phi,
                             const f16* __restrict__ gt, f16* __restrict__ Opart,
                             float2* __restrict__ ml, int nsplit, int do_ml) {
    const int qt  = blockIdx.x;   // 0..48
    const int b   = blockIdx.y;   // 0..7
    const int s   = blockIdx.z;   // 0..nsplit-1
    const int t0  = (NT * s) / nsplit;
    const int t1  = (NT * (s + 1)) / nsplit;
    const int tid = threadIdx.x;
    const int w   = tid >> 6;
    const int l   = tid & 63;
    const int lrow = l & 15;
    const int lk8  = (l >> 4) * 8;

    __shared__ alignas(16) f16 Kt[64 * 128];    // phi tile, rows=kv, 16 KB
    __shared__ alignas(16) f16 Vt[128 * 64];    // g^T tile, rows=d, 16 KB
    __shared__ alignas(16) f16 Pl[4][16 * 64];  // per-wave P tile, 8 KB

    const f16* thB = theta + (size_t)b * NPOS * CI;
    const f16* phB = phi   + (size_t)b * NPOS * CI;
    const f16* gtB = gt    + (size_t)b * CI * NPOS;

    const int q0 = qt * 64 + w * 16;

    f16x8 aq[4];
    #pragma unroll
    for (int kt = 0; kt < 4; ++kt)
        aq[kt] = *reinterpret_cast<const f16x8*>(&thB[(size_t)(q0 + lrow) * CI + kt * 32 + lk8]);

    f32x4 o[8];
    #pragma unroll
    for (int d0 = 0; d0 < 8; ++d0) o[d0] = (f32x4){0.f, 0.f, 0.f, 0.f};
    float mrow[4], lsum[4];
    #pragma unroll
    for (int j = 0; j < 4; ++j) { mrow[j] = -1e30f; lsum[j] = 0.f; }

    for (int t = t0; t < t1; ++t) {
        const int kv0 = t * 64;
        __syncthreads();

        #pragma unroll
        for (int i = 0; i < 4; ++i) {
            int c = tid + 256 * i;
            int row  = c >> 4;
            int dcol = (c & 15) * 8;
            f16x8 v = *reinterpret_cast<const f16x8*>(&phB[(size_t)(kv0 + row) * CI + dcol]);
            *reinterpret_cast<f16x8*>(&Kt[row * 128 + (dcol ^ ((row & 7) << 3))]) = v;
        }
        #pragma unroll
        for (int i = 0; i < 4; ++i) {
            int c = tid + 256 * i;
            int row  = c >> 3;
            int kcol = (c & 7) * 8;
            f16x8 v = *reinterpret_cast<const f16x8*>(&gtB[(size_t)row * NPOS + kv0 + kcol]);
            *reinterpret_cast<f16x8*>(&Vt[row * 64 + (kcol ^ ((row & 7) << 3))]) = v;
        }
        __syncthreads();

        f32x4 sreg[4];
        #pragma unroll
        for (int c0 = 0; c0 < 4; ++c0) sreg[c0] = (f32x4){0.f, 0.f, 0.f, 0.f};
        #pragma unroll
        for (int kt = 0; kt < 4; ++kt) {
            #pragma unroll
            for (int c0 = 0; c0 < 4; ++c0) {
                int krow = c0 * 16 + lrow;
                f16x8 bk = *reinterpret_cast<const f16x8*>(
                    &Kt[krow * 128 + ((kt * 32 + lk8) ^ ((krow & 7) << 3))]);
                sreg[c0] = __builtin_amdgcn_mfma_f32_16x16x32_f16(aq[kt], bk, sreg[c0], 0, 0, 0);
            }
        }

        #pragma unroll
        for (int j = 0; j < 4; ++j) {
            float rm = fmaxf(fmaxf(sreg[0][j], sreg[1][j]), fmaxf(sreg[2][j], sreg[3][j]));
            rm = fmaxf(rm, __shfl_xor(rm, 1));
            rm = fmaxf(rm, __shfl_xor(rm, 2));
            rm = fmaxf(rm, __shfl_xor(rm, 4));
            rm = fmaxf(rm, __shfl_xor(rm, 8));
            float mnew  = fmaxf(mrow[j], rm);
            float scale = __expf(mrow[j] - mnew);
            mrow[j] = mnew;
            float ps = 0.f;
            #pragma unroll
            for (int c0 = 0; c0 < 4; ++c0) {
                float p = __expf(sreg[c0][j] - mnew);
                sreg[c0][j] = p;
                ps += p;
            }
            ps += __shfl_xor(ps, 1);
            ps += __shfl_xor(ps, 2);
            ps += __shfl_xor(ps, 4);
            ps += __shfl_xor(ps, 8);
            lsum[j] = lsum[j] * scale + ps;
            #pragma unroll
            for (int d0 = 0; d0 < 8; ++d0) o[d0][j] *= scale;
            int prow = (l >> 4) * 4 + j;
            #pragma unroll
            for (int c0 = 0; c0 < 4; ++c0) {
                int kv = c0 * 16 + lrow;
                Pl[w][prow * 64 + (kv ^ ((prow & 7) << 3))] = (f16)sreg[c0][j];
            }
        }
        asm volatile("s_waitcnt lgkmcnt(0)" ::: "memory");

        #pragma unroll
        for (int kt2 = 0; kt2 < 2; ++kt2) {
            f16x8 pa = *reinterpret_cast<const f16x8*>(
                &Pl[w][lrow * 64 + ((kt2 * 32 + lk8) ^ ((lrow & 7) << 3))]);
            #pragma unroll
            for (int d0 = 0; d0 < 8; ++d0) {
                int vrow = d0 * 16 + lrow;
                f16x8 bv = *reinterpret_cast<const f16x8*>(
                    &Vt[vrow * 64 + ((kt2 * 32 + lk8) ^ ((vrow & 7) << 3))]);
                o[d0] = __builtin_amdgcn_mfma_f32_16x16x32_f16(pa, bv, o[d0], 0, 0, 0);
            }
        }
    }

    // epilogue: normalized partial O + (m, l)
    #pragma unroll
    for (int j = 0; j < 4; ++j) {
        float inv  = 1.f / lsum[j];
        int   qrow = q0 + (l >> 4) * 4 + j;
        size_t grow = (size_t)b * NPOS + qrow;
        #pragma unroll
        for (int d0 = 0; d0 < 8; ++d0) {
            int d = d0 * 16 + lrow;
            Opart[((size_t)s * MTOT + grow) * CI + d] = (f16)(o[d0][j] * inv);
        }
        if (do_ml && lrow == 0) {
            float2 v; v.x = mrow[j]; v.y = lsum[j];
            ml[(size_t)s * MTOT + grow] = v;
        }
    }
}

// ---------------------------------------------------------------------------
// Kernel 2b: merge KV-split partials.  y = sum_s w_s O_s / sum_s w_s,
//   w_s = l_s * exp(m_s - M)
// ---------------------------------------------------------------------------
__launch_bounds__(256)
__global__ void attn_merge(const f16* __restrict__ Opart, const float2* __restrict__ ml,
                           f16* __restrict__ y, int nsplit) {
    int idx = blockIdx.x * 256 + threadIdx.x;    // over MTOT*16 chunks
    int row = idx >> 4;
    int dc  = (idx & 15) * 8;
    if (row >= MTOT) return;
    float M = -1e30f;
    for (int s2 = 0; s2 < nsplit; ++s2)
        M = fmaxf(M, ml[(size_t)s2 * MTOT + row].x);
    float wgt[8];
    float L = 0.f;
    for (int s2 = 0; s2 < nsplit; ++s2) {
        float2 v = ml[(size_t)s2 * MTOT + row];
        float wv = v.y * __expf(v.x - M);
        wgt[s2] = wv; L += wv;
    }
    float invL = 1.f / L;
    float acc[8];
    #pragma unroll
    for (int j = 0; j < 8; ++j) acc[j] = 0.f;
    for (int s2 = 0; s2 < nsplit; ++s2) {
        f16x8 v = *reinterpret_cast<const f16x8*>(&Opart[((size_t)s2 * MTOT + row) * CI + dc]);
        #pragma unroll
        for (int j = 0; j < 8; ++j) acc[j] += wgt[s2] * (float)v[j];
    }
    f16x8 r;
    #pragma unroll
    for (int j = 0; j < 8; ++j) r[j] = (f16)(acc[j] * invL);
    *reinterpret_cast<f16x8*>(&y[(size_t)row * CI + dc]) = r;
}

// ---------------------------------------------------------------------------
// Kernel 3: out = x + y @ w_out + b_out   (grid.y=2; 128 cols per block)
// ---------------------------------------------------------------------------
__launch_bounds__(256)
__global__ void out_proj(const f16* __restrict__ y, const f16* __restrict__ woutT,
                         const float* __restrict__ bout, const float* __restrict__ x,
                         float* __restrict__ out) {
    const int mt  = blockIdx.x;   // 0..391
    const int ch  = blockIdx.y;   // 0..1
    const int tid = threadIdx.x;
    const int w   = tid >> 6;
    const int l   = tid & 63;
    const int lrow = l & 15;
    const int lk8  = (l >> 4) * 8;
    const int m0   = mt * 64 + w * 16;

    f16x8 aq[4];
    #pragma unroll
    for (int kt = 0; kt < 4; ++kt)
        aq[kt] = *reinterpret_cast<const f16x8*>(&y[(size_t)(m0 + lrow) * CI + kt * 32 + lk8]);

    for (int cc = 0; cc < 2; ++cc) {
        const int cbase = ch * 128 + cc * 64;
        f32x4 acc[4];
        #pragma unroll
        for (int c0 = 0; c0 < 4; ++c0) acc[c0] = (f32x4){0.f, 0.f, 0.f, 0.f};
        #pragma unroll
        for (int kt = 0; kt < 4; ++kt) {
            #pragma unroll
            for (int c0 = 0; c0 < 4; ++c0) {
                int oc = cbase + c0 * 16 + lrow;
                f16x8 bb = *reinterpret_cast<const f16x8*>(&woutT[oc * CI + kt * 32 + lk8]);
                acc[c0] = __builtin_amdgcn_mfma_f32_16x16x32_f16(aq[kt], bb, acc[c0], 0, 0, 0);
            }
        }
        #pragma unroll
        for (int c0 = 0; c0 < 4; ++c0) {
            int oc = cbase + c0 * 16 + lrow;
            float bias = bout[oc];
            #pragma unroll
            for (int j = 0; j < 4; ++j) {
                size_t m = (size_t)m0 + (l >> 4) * 4 + j;
                out[m * CO + oc] = acc[c0][j] + bias + x[m * CO + oc];
            }
        }
    }
}

// ---------------------------------------------------------------------------
extern "C" void kernel_launch(void* const* d_in, const int* in_sizes, int n_in,
                              void* d_out, int out_size, void* d_ws, size_t ws_size,
                              hipStream_t stream) {
    const float* x  = (const float*)d_in[0];
    const float* wt = (const float*)d_in[1];
    const float* bt = (const float*)d_in[2];
    const float* wp = (const float*)d_in[3];
    const float* bp = (const float*)d_in[4];
    const float* wg = (const float*)d_in[5];
    const float* bg = (const float*)d_in[6];
    const float* wo = (const float*)d_in[7];
    const float* bo = (const float*)d_in[8];
    float* out = (float*)d_out;

    char* ws = (char*)d_ws;
    const size_t SZ_PROJT = 384 * 256 * sizeof(f16);   // 196608
    const size_t SZ_OUTT  = 256 * 128 * sizeof(f16);   // 65536
    const size_t SZ_MAT   = (size_t)MTOT * CI * sizeof(f16);   // 6422528
    const size_t SZ_ML    = (size_t)MTOT * sizeof(float2);     // 200704
    const size_t BASE3    = SZ_PROJT + SZ_OUTT;

    f16* wprojT = (f16*)ws;
    f16* woutT  = (f16*)(ws + SZ_PROJT);
    f16* theta  = (f16*)(ws + BASE3);
    f16* phi    = (f16*)(ws + BASE3 + SZ_MAT);
    f16* gt     = (f16*)(ws + BASE3 + 2 * SZ_MAT);
    char* tail  = ws + BASE3 + 3 * SZ_MAT;
    size_t tail_avail = (ws_size > (size_t)(tail - ws)) ? ws_size - (size_t)(tail - ws) : 0;

    int nsplit = 1;
    if (tail_avail >= 4 * (SZ_MAT + SZ_ML)) nsplit = 4;
    else if (tail_avail >= 2 * (SZ_MAT + SZ_ML)) nsplit = 2;

    f16*    Opart = (f16*)tail;
    float2* ml    = (float2*)(tail + (size_t)nsplit * SZ_MAT);
    // after the merge, theta is dead: y aliases theta's slot when nsplit>1
    f16* y = (nsplit > 1) ? theta : Opart;

    hipLaunchKernelGGL(prep_weights, dim3(640), dim3(256), 0, stream,
                       wt, wp, wg, wo, wprojT, woutT);
    hipLaunchKernelGGL(proj_gemm, dim3(392), dim3(256), 0, stream,
                       x, wprojT, bt, bp, bg, theta, phi, gt);
    hipLaunchKernelGGL(attn_partial, dim3(NT, B_SZ, nsplit), dim3(256), 0, stream,
                       theta, phi, gt, Opart, ml, nsplit, (nsplit > 1) ? 1 : 0);
    if (nsplit > 1)
        hipLaunchKernelGGL(attn_merge, dim3((MTOT * 16 + 255) / 256), dim3(256), 0, stream,
                           Opart, ml, y, nsplit);
    hipLaunchKernelGGL(out_proj, dim3(392, 2), dim3(256), 0, stream,
                       y, woutT, bo, x, out);
}